// Round 1
// baseline (778.006 us; speedup 1.0000x reference)
//
#include <hip/hip_runtime.h>
#include <math.h>

#define N_NODES 50000
#define N_EDGES 150000
#define EMB 64
#define IN_DIM 32
#define LN_EPS 1e-5f

#define TILE_M 64
#define KC 64

// ---------------------------------------------------------------------------
// prep: Wt[fk][e] = W[(e*64+f)*32+k], fk = f*32+k  (2048x64 f32, 512 KB)
//       bT[f][e]  = b[e*64+f]                      (64x64 f32, 16 KB)
// ---------------------------------------------------------------------------
__global__ void prep_kernel(const float* __restrict__ W, const float* __restrict__ b,
                            float* __restrict__ Wt, float* __restrict__ bT) {
    int tid = blockIdx.x * 256 + threadIdx.x;
    if (tid < 2048 * 64) {
        int e = tid & 63, fk = tid >> 6;
        int f = fk >> 5, k = fk & 31;
        Wt[tid] = W[(e * 64 + f) * 32 + k];
    } else {
        int i = tid - 2048 * 64;
        if (i < 64 * 64) {
            int e = i & 63, f = i >> 6;
            bT[i] = b[e * 64 + f];
        }
    }
}

// ---------------------------------------------------------------------------
// init: out = h  (residual base; edge kernel atomically accumulates into it)
// ---------------------------------------------------------------------------
__global__ void init_kernel(const float* __restrict__ h, float* __restrict__ out) {
    int tid = blockIdx.x * 256 + threadIdx.x;
    ((float4*)out)[tid] = ((const float4*)h)[tid];
}

// ---------------------------------------------------------------------------
// edge: per 64-edge tile, msg = A @ B with A[m, f*32+k] = h_j[m,f]*ea[m,k]
//       (built in LDS), B = Wt chunks; chunk 32 is the bias term (A=h_j, B=bT).
//       Scatter-add msg rows to out[src].
// ---------------------------------------------------------------------------
__launch_bounds__(256, 2)
__global__ void edge_kernel(const float* __restrict__ ea,   // [N_EDGES][32]
                            const float* __restrict__ h,    // [N_NODES][64]
                            const int*   __restrict__ ei,   // [2][N_EDGES]
                            const float* __restrict__ Wt,   // [2048][64]
                            const float* __restrict__ bT,   // [64][64]
                            float* __restrict__ out)        // [N_NODES][64]
{
    __shared__ float s_ea[TILE_M][34];   // stride 34: 2-way (free) on fixed-k reads
    __shared__ float s_hj[TILE_M][66];   // stride 66: 2-way (free) on fixed-f reads
    __shared__ float s_A[KC][TILE_M];    // k-major: b128 GEMM reads, row-seq writes
    __shared__ float s_B[KC][EMB];
    __shared__ int   s_src[TILE_M];

    const int t = threadIdx.x;
    const int m_base = blockIdx.x * TILE_M;

    // ---- stage ea (64x32, float2 granularity) ----
    for (int i = t; i < TILE_M * 16; i += 256) {
        int m = i >> 4;
        int c = (i & 15) * 2;
        int gm = m_base + m;
        float2 v = make_float2(0.f, 0.f);
        if (gm < N_EDGES) v = *(const float2*)&ea[gm * 32 + c];
        s_ea[m][c] = v.x; s_ea[m][c + 1] = v.y;
    }
    // ---- gather h_j = h[dst] (64x64, float2) ----
    for (int i = t; i < TILE_M * 32; i += 256) {
        int m = i >> 5;
        int c = (i & 31) * 2;
        int gm = m_base + m;
        float2 v = make_float2(0.f, 0.f);
        if (gm < N_EDGES) {
            int dst = ei[N_EDGES + gm];
            v = *(const float2*)&h[dst * 64 + c];
        }
        s_hj[m][c] = v.x; s_hj[m][c + 1] = v.y;
    }
    if (t < TILE_M) {
        int gm = m_base + t;
        s_src[t] = (gm < N_EDGES) ? ei[gm] : -1;
    }

    const int eg = t & 15, mg = t >> 4;
    const int e0 = eg * 4, m0 = mg * 4;
    float acc[4][4] = {};

    __syncthreads();

    for (int c = 0; c < 33; ++c) {
        // ---- stage B chunk (coalesced from Wt / bT, 16 KB) ----
        const float* src = (c < 32) ? (Wt + c * KC * EMB) : bT;
        for (int i = t; i < KC * EMB / 4; i += 256) {
            ((float4*)&s_B[0][0])[i] = ((const float4*)src)[i];
        }
        // ---- build A chunk: wave w handles kk = w + 4j, lane = m ----
        {
            int m = t & 63;
            int kb = t >> 6;
            if (c < 32) {
                int kidx0 = c * KC;
                #pragma unroll
                for (int j = 0; j < 16; ++j) {
                    int kk = kb + 4 * j;
                    int kidx = kidx0 + kk;
                    s_A[kk][m] = s_hj[m][kidx >> 5] * s_ea[m][kidx & 31];
                }
            } else {  // bias chunk: A = h_j
                #pragma unroll
                for (int j = 0; j < 16; ++j) {
                    int kk = kb + 4 * j;
                    s_A[kk][m] = s_hj[m][kk];
                }
            }
        }
        __syncthreads();

        // ---- GEMM: 4x4 register tile per thread ----
        #pragma unroll 8
        for (int kk = 0; kk < KC; ++kk) {
            float4 av = *(const float4*)&s_A[kk][m0];
            float4 bv = *(const float4*)&s_B[kk][e0];
            acc[0][0] = fmaf(av.x, bv.x, acc[0][0]);
            acc[0][1] = fmaf(av.x, bv.y, acc[0][1]);
            acc[0][2] = fmaf(av.x, bv.z, acc[0][2]);
            acc[0][3] = fmaf(av.x, bv.w, acc[0][3]);
            acc[1][0] = fmaf(av.y, bv.x, acc[1][0]);
            acc[1][1] = fmaf(av.y, bv.y, acc[1][1]);
            acc[1][2] = fmaf(av.y, bv.z, acc[1][2]);
            acc[1][3] = fmaf(av.y, bv.w, acc[1][3]);
            acc[2][0] = fmaf(av.z, bv.x, acc[2][0]);
            acc[2][1] = fmaf(av.z, bv.y, acc[2][1]);
            acc[2][2] = fmaf(av.z, bv.z, acc[2][2]);
            acc[2][3] = fmaf(av.z, bv.w, acc[2][3]);
            acc[3][0] = fmaf(av.w, bv.x, acc[3][0]);
            acc[3][1] = fmaf(av.w, bv.y, acc[3][1]);
            acc[3][2] = fmaf(av.w, bv.z, acc[3][2]);
            acc[3][3] = fmaf(av.w, bv.w, acc[3][3]);
        }
        __syncthreads();
    }

    // ---- scatter-add to out[src] ----
    #pragma unroll
    for (int i = 0; i < 4; ++i) {
        int srcn = s_src[m0 + i];
        if (srcn >= 0) {
            #pragma unroll
            for (int j = 0; j < 4; ++j)
                atomicAdd(&out[srcn * 64 + e0 + j], acc[i][j]);
        }
    }
}

// ---------------------------------------------------------------------------
// ln: in-place LayerNorm, one wave (64 lanes) per row
// ---------------------------------------------------------------------------
__global__ void ln_kernel(const float* __restrict__ gamma, const float* __restrict__ beta,
                          float* __restrict__ out) {
    int row = blockIdx.x * 4 + (threadIdx.x >> 6);
    int lane = threadIdx.x & 63;
    if (row >= N_NODES) return;
    float x = out[row * 64 + lane];
    float s = x;
    #pragma unroll
    for (int o = 32; o; o >>= 1) s += __shfl_xor(s, o);
    float mu = s * (1.0f / 64.0f);
    float d = x - mu;
    float v = d * d;
    #pragma unroll
    for (int o = 32; o; o >>= 1) v += __shfl_xor(v, o);
    float var = v * (1.0f / 64.0f);
    float r = rsqrtf(var + LN_EPS);
    out[row * 64 + lane] = d * r * gamma[lane] + beta[lane];
}

// ---------------------------------------------------------------------------
extern "C" void kernel_launch(void* const* d_in, const int* in_sizes, int n_in,
                              void* d_out, int out_size, void* d_ws, size_t ws_size,
                              hipStream_t stream) {
    const float* h     = (const float*)d_in[0];
    const float* ea    = (const float*)d_in[1];
    const float* W     = (const float*)d_in[2];
    const float* b     = (const float*)d_in[3];
    const float* gamma = (const float*)d_in[4];
    const float* beta  = (const float*)d_in[5];
    const int*   ei    = (const int*)d_in[6];
    float* out = (float*)d_out;

    float* Wt = (float*)d_ws;            // 512 KB
    float* bT = Wt + 2048 * 64;          // +16 KB

    prep_kernel<<<528, 256, 0, stream>>>(W, b, Wt, bT);
    init_kernel<<<(N_NODES * EMB / 4 + 255) / 256, 256, 0, stream>>>(h, out);
    edge_kernel<<<(N_EDGES + TILE_M - 1) / TILE_M, 256, 0, stream>>>(ea, h, ei, Wt, bT, out);
    ln_kernel<<<(N_NODES + 3) / 4, 256, 0, stream>>>(gamma, beta, out);
}

// Round 3
// 171.354 us; speedup vs baseline: 4.5403x; 4.5403x over previous
//
#include <hip/hip_runtime.h>
#include <math.h>

#define N_NODES 50000
#define N_EDGES 150000
#define LN_EPS 1e-5f

#define BM 128   // edge rows per block
#define WM 64    // edge rows per wave

typedef _Float16 f16x8 __attribute__((ext_vector_type(8)));
typedef float    f32x4 __attribute__((ext_vector_type(4)));

// ---------------------------------------------------------------------------
// prep: WtF in exact MFMA B-fragment order.
//   index ((c*4 + nb)*64 + lane)*8 + i  (66 chunks, 4 n-blocks, 64 lanes, 8 f16)
//   k = (lane>>4)*8 + i (0..31), e = nb*16 + (lane&15)
//   c < 64 : value = W[(e*64 + c)*32 + k]      (product chunks, f == c)
//   c >= 64: value = b[e*64 + (c-64)*32 + k]   (bias chunks, A = h_j)
// ---------------------------------------------------------------------------
__global__ void prep_kernel(const float* __restrict__ W, const float* __restrict__ b,
                            _Float16* __restrict__ WtF) {
    int tid = blockIdx.x * 256 + threadIdx.x;
    if (tid >= 66 * 4 * 64 * 8) return;
    int i  = tid & 7;
    int l  = (tid >> 3) & 63;
    int nb = (tid >> 9) & 3;
    int c  = tid >> 11;
    int k  = ((l >> 4) << 3) + i;
    int e  = nb * 16 + (l & 15);
    float v;
    if (c < 64) v = W[(e * 64 + c) * 32 + k];
    else        v = b[e * 64 + (c - 64) * 32 + k];
    WtF[tid] = (_Float16)v;
}

// ---------------------------------------------------------------------------
// init: out = h (residual base; edge kernel atomically accumulates)
// ---------------------------------------------------------------------------
__global__ void init_kernel(const float* __restrict__ h, float* __restrict__ out) {
    int tid = blockIdx.x * 256 + threadIdx.x;
    ((float4*)out)[tid] = ((const float4*)h)[tid];
}

// ---------------------------------------------------------------------------
// edge: fp16 MFMA GEMM, A-fragments built in registers from hj (LDS) x ea (regs)
// ---------------------------------------------------------------------------
__launch_bounds__(128, 2)
__global__ void edge_kernel(const float* __restrict__ ea,   // [N_EDGES][32]
                            const float* __restrict__ h,    // [N_NODES][64]
                            const int*   __restrict__ ei,   // [2][N_EDGES]
                            const f16x8* __restrict__ WtF,  // fragment-major
                            float* __restrict__ out)        // [N_NODES][64]
{
    __shared__ float s_hj[BM][68];   // pad 68: b128-aligned rows, 2-way-free col reads
    __shared__ int   s_src[BM];

    const int t = threadIdx.x;
    const int m_base = blockIdx.x * BM;

    // ---- stage gathered h_j rows + src indices (one row per thread) ----
    {
        int gm = m_base + t;
        if (gm < N_EDGES) {
            s_src[t] = ei[gm];
            const float4* hr = (const float4*)&h[(size_t)ei[N_EDGES + gm] * 64];
            #pragma unroll
            for (int j = 0; j < 16; ++j)
                *(float4*)&s_hj[t][j * 4] = hr[j];
        } else {
            s_src[t] = -1;
            float4 z = make_float4(0.f, 0.f, 0.f, 0.f);
            #pragma unroll
            for (int j = 0; j < 16; ++j)
                *(float4*)&s_hj[t][j * 4] = z;
        }
    }

    const int lane = t & 63;
    const int w    = t >> 6;
    const int r16  = lane & 15;
    const int g    = lane >> 4;
    const int k0   = g * 8;
    const int row0 = w * WM;

    // ---- ea A-slice registers: fixed per lane for the whole K loop ----
    float eareg[4][8];
    #pragma unroll
    for (int a = 0; a < 4; ++a) {
        int gm = m_base + row0 + a * 16 + r16;
        if (gm < N_EDGES) {
            float4 v0 = *(const float4*)&ea[(size_t)gm * 32 + k0];
            float4 v1 = *(const float4*)&ea[(size_t)gm * 32 + k0 + 4];
            eareg[a][0] = v0.x; eareg[a][1] = v0.y; eareg[a][2] = v0.z; eareg[a][3] = v0.w;
            eareg[a][4] = v1.x; eareg[a][5] = v1.y; eareg[a][6] = v1.z; eareg[a][7] = v1.w;
        } else {
            #pragma unroll
            for (int i = 0; i < 8; ++i) eareg[a][i] = 0.f;
        }
    }

    f32x4 acc[4][4];
    #pragma unroll
    for (int a = 0; a < 4; ++a)
        #pragma unroll
        for (int nb = 0; nb < 4; ++nb)
            acc[a][nb] = (f32x4){0.f, 0.f, 0.f, 0.f};

    __syncthreads();   // only barrier in the kernel

    // ---- preload step 0 ----
    f16x8 bcur[4], bnxt[4];
    float hc[4], hn[4];
    #pragma unroll
    for (int nb = 0; nb < 4; ++nb) bcur[nb] = WtF[nb * 64 + lane];
    #pragma unroll
    for (int a = 0; a < 4; ++a) hc[a] = s_hj[row0 + a * 16 + r16][0];

    // ---- main loop: 64 product chunks, 2-step software pipeline ----
    for (int c2 = 0; c2 < 32; ++c2) {
        const int c = 2 * c2;
        // step c (uses bcur/hc), prefetch c+1
        #pragma unroll
        for (int nb = 0; nb < 4; ++nb) bnxt[nb] = WtF[((c + 1) * 4 + nb) * 64 + lane];
        #pragma unroll
        for (int a = 0; a < 4; ++a) hn[a] = s_hj[row0 + a * 16 + r16][c + 1];
        #pragma unroll
        for (int a = 0; a < 4; ++a) {
            f16x8 va;
            #pragma unroll
            for (int i = 0; i < 4; ++i) {
                auto p = __builtin_amdgcn_cvt_pkrtz(eareg[a][2 * i]     * hc[a],
                                                    eareg[a][2 * i + 1] * hc[a]);
                va[2 * i]     = (_Float16)p[0];
                va[2 * i + 1] = (_Float16)p[1];
            }
            #pragma unroll
            for (int nb = 0; nb < 4; ++nb)
                acc[a][nb] = __builtin_amdgcn_mfma_f32_16x16x32_f16(va, bcur[nb], acc[a][nb], 0, 0, 0);
        }
        // step c+1 (uses bnxt/hn), prefetch c+2 (c+2==64 → bias chunk for epilogue)
        #pragma unroll
        for (int nb = 0; nb < 4; ++nb) bcur[nb] = WtF[((c + 2) * 4 + nb) * 64 + lane];
        {
            const int cn = (c + 2 < 64) ? (c + 2) : 0;   // value unused when clamped
            #pragma unroll
            for (int a = 0; a < 4; ++a) hc[a] = s_hj[row0 + a * 16 + r16][cn];
        }
        #pragma unroll
        for (int a = 0; a < 4; ++a) {
            f16x8 va;
            #pragma unroll
            for (int i = 0; i < 4; ++i) {
                auto p = __builtin_amdgcn_cvt_pkrtz(eareg[a][2 * i]     * hn[a],
                                                    eareg[a][2 * i + 1] * hn[a]);
                va[2 * i]     = (_Float16)p[0];
                va[2 * i + 1] = (_Float16)p[1];
            }
            #pragma unroll
            for (int nb = 0; nb < 4; ++nb)
                acc[a][nb] = __builtin_amdgcn_mfma_f32_16x16x32_f16(va, bnxt[nb], acc[a][nb], 0, 0, 0);
        }
    }

    // ---- bias chunks 64 (uses bcur, prefetched) and 65: A = h_j directly ----
    #pragma unroll
    for (int nb = 0; nb < 4; ++nb) bnxt[nb] = WtF[(65 * 4 + nb) * 64 + lane];
    #pragma unroll
    for (int a = 0; a < 4; ++a) {
        f16x8 va;
        #pragma unroll
        for (int i = 0; i < 8; ++i) va[i] = (_Float16)s_hj[row0 + a * 16 + r16][k0 + i];
        #pragma unroll
        for (int nb = 0; nb < 4; ++nb)
            acc[a][nb] = __builtin_amdgcn_mfma_f32_16x16x32_f16(va, bcur[nb], acc[a][nb], 0, 0, 0);
    }
    #pragma unroll
    for (int a = 0; a < 4; ++a) {
        f16x8 va;
        #pragma unroll
        for (int i = 0; i < 8; ++i) va[i] = (_Float16)s_hj[row0 + a * 16 + r16][32 + k0 + i];
        #pragma unroll
        for (int nb = 0; nb < 4; ++nb)
            acc[a][nb] = __builtin_amdgcn_mfma_f32_16x16x32_f16(va, bnxt[nb], acc[a][nb], 0, 0, 0);
    }

    // ---- scatter-add (C/D layout: col = lane&15, row = (lane>>4)*4 + reg) ----
    #pragma unroll
    for (int a = 0; a < 4; ++a) {
        #pragma unroll
        for (int r = 0; r < 4; ++r) {
            int srcn = s_src[row0 + a * 16 + g * 4 + r];
            if (srcn >= 0) {
                #pragma unroll
                for (int nb = 0; nb < 4; ++nb)
                    atomicAdd(&out[(size_t)srcn * 64 + nb * 16 + r16], acc[a][nb][r]);
            }
        }
    }
}

// ---------------------------------------------------------------------------
// ln: in-place LayerNorm, one wave per row
// ---------------------------------------------------------------------------
__global__ void ln_kernel(const float* __restrict__ gamma, const float* __restrict__ beta,
                          float* __restrict__ out) {
    int row = blockIdx.x * 4 + (threadIdx.x >> 6);
    int lane = threadIdx.x & 63;
    if (row >= N_NODES) return;
    float x = out[row * 64 + lane];
    float s = x;
    #pragma unroll
    for (int o = 32; o; o >>= 1) s += __shfl_xor(s, o);
    float mu = s * (1.0f / 64.0f);
    float d = x - mu;
    float v = d * d;
    #pragma unroll
    for (int o = 32; o; o >>= 1) v += __shfl_xor(v, o);
    float var = v * (1.0f / 64.0f);
    float r = rsqrtf(var + LN_EPS);
    out[row * 64 + lane] = d * r * gamma[lane] + beta[lane];
}

// ---------------------------------------------------------------------------
extern "C" void kernel_launch(void* const* d_in, const int* in_sizes, int n_in,
                              void* d_out, int out_size, void* d_ws, size_t ws_size,
                              hipStream_t stream) {
    const float* h     = (const float*)d_in[0];
    const float* ea    = (const float*)d_in[1];
    const float* W     = (const float*)d_in[2];
    const float* b     = (const float*)d_in[3];
    const float* gamma = (const float*)d_in[4];
    const float* beta  = (const float*)d_in[5];
    const int*   ei    = (const int*)d_in[6];
    float* out = (float*)d_out;

    _Float16* WtF = (_Float16*)d_ws;   // 66*4*64*8 f16 = 264 KB

    prep_kernel<<<528, 256, 0, stream>>>(W, b, WtF);
    init_kernel<<<(N_NODES * 64 / 4 + 255) / 256, 256, 0, stream>>>(h, out);
    edge_kernel<<<(N_EDGES + BM - 1) / BM, 128, 0, stream>>>(ea, h, ei, (const f16x8*)WtF, out);
    ln_kernel<<<(N_NODES + 3) / 4, 256, 0, stream>>>(gamma, beta, out);
}

// Round 4
// 165.735 us; speedup vs baseline: 4.6943x; 1.0339x over previous
//
#include <hip/hip_runtime.h>
#include <math.h>

#define N_NODES 50000
#define N_EDGES 150000
#define LN_EPS 1e-5f

#define BM 128   // edge rows per block
#define WM 32    // edge rows per wave (4 waves)

typedef _Float16 f16x8 __attribute__((ext_vector_type(8)));
typedef float    f32x4 __attribute__((ext_vector_type(4)));

// ---------------------------------------------------------------------------
// prep: WtF in exact MFMA B-fragment order, one f16x8 (16B) store per thread.
//   frag index (c*4 + nb)*64 + l ; element i: k = (l>>4)*8 + i, e = nb*16 + (l&15)
//   c < 64 : W[(e*64 + c)*32 + k]      (product chunks, f == c)
//   c >= 64: b[e*64 + (c-64)*32 + k]   (bias chunks, A = h_j)
// ---------------------------------------------------------------------------
__global__ void prep_kernel(const float* __restrict__ W, const float* __restrict__ b,
                            f16x8* __restrict__ WtF) {
    int tid = blockIdx.x * 256 + threadIdx.x;
    if (tid >= 66 * 4 * 64) return;
    int l  = tid & 63;
    int nb = (tid >> 6) & 3;
    int c  = tid >> 8;
    int k0 = (l >> 4) << 3;
    int e  = nb * 16 + (l & 15);
    const float* src = (c < 64) ? &W[(e * 64 + c) * 32 + k0]
                                : &b[e * 64 + (c - 64) * 32 + k0];
    float4 v0 = *(const float4*)src;
    float4 v1 = *(const float4*)(src + 4);
    f16x8 o;
    o[0] = (_Float16)v0.x; o[1] = (_Float16)v0.y; o[2] = (_Float16)v0.z; o[3] = (_Float16)v0.w;
    o[4] = (_Float16)v1.x; o[5] = (_Float16)v1.y; o[6] = (_Float16)v1.z; o[7] = (_Float16)v1.w;
    WtF[tid] = o;
}

// ---------------------------------------------------------------------------
// init: out = h (residual base; edge kernel atomically accumulates)
// ---------------------------------------------------------------------------
__global__ void init_kernel(const float* __restrict__ h, float* __restrict__ out) {
    int tid = blockIdx.x * 256 + threadIdx.x;
    ((float4*)out)[tid] = ((const float4*)h)[tid];
}

// ---------------------------------------------------------------------------
// edge: fp16 MFMA GEMM. 4 waves x 32 rows, 3-deep register B-prefetch.
// A[m, c*32+k] = hj[m,c] * ea[m,k] built in regs; B direct from L2 (WtF).
// ---------------------------------------------------------------------------
__launch_bounds__(256, 4)
__global__ void edge_kernel(const float* __restrict__ ea,   // [N_EDGES][32]
                            const float* __restrict__ h,    // [N_NODES][64]
                            const int*   __restrict__ ei,   // [2][N_EDGES]
                            const f16x8* __restrict__ WtF,  // fragment-major
                            float* __restrict__ out)        // [N_NODES][64]
{
    __shared__ float s_hj[BM][68];   // stride 68: b128-aligned rows, <=2-way (free)
    __shared__ int   s_src[BM];

    const int t = threadIdx.x;
    const int m_base = blockIdx.x * BM;

    // ---- stage gathered h_j rows + src indices (two threads per row) ----
    {
        int row  = t >> 1;
        int half = t & 1;
        int gm   = m_base + row;
        if (gm < N_EDGES) {
            if (half == 0) s_src[row] = ei[gm];
            const float4* hr = (const float4*)&h[(size_t)ei[N_EDGES + gm] * 64 + half * 32];
            #pragma unroll
            for (int j = 0; j < 8; ++j)
                *(float4*)&s_hj[row][half * 32 + j * 4] = hr[j];
        } else {
            if (half == 0) s_src[row] = -1;
            float4 z = make_float4(0.f, 0.f, 0.f, 0.f);
            #pragma unroll
            for (int j = 0; j < 8; ++j)
                *(float4*)&s_hj[row][half * 32 + j * 4] = z;
        }
    }

    const int lane = t & 63;
    const int w    = t >> 6;
    const int r16  = lane & 15;
    const int g    = lane >> 4;
    const int k0   = g * 8;
    const int row0 = w * WM;
    const int rA   = row0 + r16;        // a = 0 row
    const int rB   = row0 + 16 + r16;   // a = 1 row

    // ---- ea A-slice registers: fixed per lane for the whole K loop ----
    float eareg[2][8];
    #pragma unroll
    for (int a = 0; a < 2; ++a) {
        int gm = m_base + row0 + a * 16 + r16;
        if (gm < N_EDGES) {
            float4 v0 = *(const float4*)&ea[(size_t)gm * 32 + k0];
            float4 v1 = *(const float4*)&ea[(size_t)gm * 32 + k0 + 4];
            eareg[a][0] = v0.x; eareg[a][1] = v0.y; eareg[a][2] = v0.z; eareg[a][3] = v0.w;
            eareg[a][4] = v1.x; eareg[a][5] = v1.y; eareg[a][6] = v1.z; eareg[a][7] = v1.w;
        } else {
            #pragma unroll
            for (int i = 0; i < 8; ++i) eareg[a][i] = 0.f;
        }
    }

    f32x4 acc[2][4];
    #pragma unroll
    for (int a = 0; a < 2; ++a)
        #pragma unroll
        for (int nb = 0; nb < 4; ++nb)
            acc[a][nb] = (f32x4){0.f, 0.f, 0.f, 0.f};

    __syncthreads();   // only barrier in the kernel

    // ---- B prefetch buffers (3-deep) ----
    f16x8 b0[4], b1[4], b2[4];
    #pragma unroll
    for (int nb = 0; nb < 4; ++nb) b0[nb] = WtF[(0 * 4 + nb) * 64 + lane];
    #pragma unroll
    for (int nb = 0; nb < 4; ++nb) b1[nb] = WtF[(1 * 4 + nb) * 64 + lane];
    #pragma unroll
    for (int nb = 0; nb < 4; ++nb) b2[nb] = WtF[(2 * 4 + nb) * 64 + lane];

    float hc0 = s_hj[rA][0];
    float hc1 = s_hj[rB][0];

    // product-chunk step: compute chunk c with B-regs bb, read hj col c+1
    auto step = [&](int c, f16x8* bb, bool loadnext) {
        float hn0 = 0.f, hn1 = 0.f;
        if (loadnext) { hn0 = s_hj[rA][c + 1]; hn1 = s_hj[rB][c + 1]; }
        {
            f16x8 va;
            #pragma unroll
            for (int i = 0; i < 4; ++i) {
                auto p = __builtin_amdgcn_cvt_pkrtz(eareg[0][2 * i]     * hc0,
                                                    eareg[0][2 * i + 1] * hc0);
                va[2 * i] = (_Float16)p[0]; va[2 * i + 1] = (_Float16)p[1];
            }
            #pragma unroll
            for (int nb = 0; nb < 4; ++nb)
                acc[0][nb] = __builtin_amdgcn_mfma_f32_16x16x32_f16(va, bb[nb], acc[0][nb], 0, 0, 0);
        }
        {
            f16x8 va;
            #pragma unroll
            for (int i = 0; i < 4; ++i) {
                auto p = __builtin_amdgcn_cvt_pkrtz(eareg[1][2 * i]     * hc1,
                                                    eareg[1][2 * i + 1] * hc1);
                va[2 * i] = (_Float16)p[0]; va[2 * i + 1] = (_Float16)p[1];
            }
            #pragma unroll
            for (int nb = 0; nb < 4; ++nb)
                acc[1][nb] = __builtin_amdgcn_mfma_f32_16x16x32_f16(va, bb[nb], acc[1][nb], 0, 0, 0);
        }
        hc0 = hn0; hc1 = hn1;
    };

    // ---- main loop: 21 triples cover product chunks 0..62; prefetch to 65 ----
    for (int c = 0; c < 63; c += 3) {
        step(c, b0, true);
        #pragma unroll
        for (int nb = 0; nb < 4; ++nb) b0[nb] = WtF[((c + 3) * 4 + nb) * 64 + lane];
        step(c + 1, b1, true);
        #pragma unroll
        for (int nb = 0; nb < 4; ++nb) b1[nb] = WtF[((c + 4) * 4 + nb) * 64 + lane];
        step(c + 2, b2, true);
        #pragma unroll
        for (int nb = 0; nb < 4; ++nb) b2[nb] = WtF[((c + 5) * 4 + nb) * 64 + lane];
    }
    // after loop: b0 = chunk 63 (product), b1 = 64 (bias), b2 = 65 (bias)
    step(63, b0, false);

    // ---- bias chunks: A = h_j in f16 ----
    {
        f16x8 va;
        #pragma unroll
        for (int i = 0; i < 4; ++i) {
            auto p = __builtin_amdgcn_cvt_pkrtz(s_hj[rA][k0 + 2 * i], s_hj[rA][k0 + 2 * i + 1]);
            va[2 * i] = (_Float16)p[0]; va[2 * i + 1] = (_Float16)p[1];
        }
        #pragma unroll
        for (int nb = 0; nb < 4; ++nb)
            acc[0][nb] = __builtin_amdgcn_mfma_f32_16x16x32_f16(va, b1[nb], acc[0][nb], 0, 0, 0);
        #pragma unroll
        for (int i = 0; i < 4; ++i) {
            auto p = __builtin_amdgcn_cvt_pkrtz(s_hj[rB][k0 + 2 * i], s_hj[rB][k0 + 2 * i + 1]);
            va[2 * i] = (_Float16)p[0]; va[2 * i + 1] = (_Float16)p[1];
        }
        #pragma unroll
        for (int nb = 0; nb < 4; ++nb)
            acc[1][nb] = __builtin_amdgcn_mfma_f32_16x16x32_f16(va, b1[nb], acc[1][nb], 0, 0, 0);
    }
    {
        f16x8 va;
        #pragma unroll
        for (int i = 0; i < 4; ++i) {
            auto p = __builtin_amdgcn_cvt_pkrtz(s_hj[rA][32 + k0 + 2 * i], s_hj[rA][32 + k0 + 2 * i + 1]);
            va[2 * i] = (_Float16)p[0]; va[2 * i + 1] = (_Float16)p[1];
        }
        #pragma unroll
        for (int nb = 0; nb < 4; ++nb)
            acc[0][nb] = __builtin_amdgcn_mfma_f32_16x16x32_f16(va, b2[nb], acc[0][nb], 0, 0, 0);
        #pragma unroll
        for (int i = 0; i < 4; ++i) {
            auto p = __builtin_amdgcn_cvt_pkrtz(s_hj[rB][32 + k0 + 2 * i], s_hj[rB][32 + k0 + 2 * i + 1]);
            va[2 * i] = (_Float16)p[0]; va[2 * i + 1] = (_Float16)p[1];
        }
        #pragma unroll
        for (int nb = 0; nb < 4; ++nb)
            acc[1][nb] = __builtin_amdgcn_mfma_f32_16x16x32_f16(va, b2[nb], acc[1][nb], 0, 0, 0);
    }

    // ---- scatter-add (C/D layout: col = lane&15, row = (lane>>4)*4 + reg) ----
    #pragma unroll
    for (int a = 0; a < 2; ++a) {
        #pragma unroll
        for (int r = 0; r < 4; ++r) {
            int srcn = s_src[row0 + a * 16 + g * 4 + r];
            if (srcn >= 0) {
                #pragma unroll
                for (int nb = 0; nb < 4; ++nb)
                    atomicAdd(&out[(size_t)srcn * 64 + nb * 16 + r16], acc[a][nb][r]);
            }
        }
    }
}

// ---------------------------------------------------------------------------
// ln: in-place LayerNorm, one wave per row
// ---------------------------------------------------------------------------
__global__ void ln_kernel(const float* __restrict__ gamma, const float* __restrict__ beta,
                          float* __restrict__ out) {
    int row = blockIdx.x * 4 + (threadIdx.x >> 6);
    int lane = threadIdx.x & 63;
    if (row >= N_NODES) return;
    float x = out[row * 64 + lane];
    float s = x;
    #pragma unroll
    for (int o = 32; o; o >>= 1) s += __shfl_xor(s, o);
    float mu = s * (1.0f / 64.0f);
    float d = x - mu;
    float v = d * d;
    #pragma unroll
    for (int o = 32; o; o >>= 1) v += __shfl_xor(v, o);
    float var = v * (1.0f / 64.0f);
    float r = rsqrtf(var + LN_EPS);
    out[row * 64 + lane] = d * r * gamma[lane] + beta[lane];
}

// ---------------------------------------------------------------------------
extern "C" void kernel_launch(void* const* d_in, const int* in_sizes, int n_in,
                              void* d_out, int out_size, void* d_ws, size_t ws_size,
                              hipStream_t stream) {
    const float* h     = (const float*)d_in[0];
    const float* ea    = (const float*)d_in[1];
    const float* W     = (const float*)d_in[2];
    const float* b     = (const float*)d_in[3];
    const float* gamma = (const float*)d_in[4];
    const float* beta  = (const float*)d_in[5];
    const int*   ei    = (const int*)d_in[6];
    float* out = (float*)d_out;

    f16x8* WtF = (f16x8*)d_ws;   // 66*4*64 f16x8 = 264 KB

    prep_kernel<<<66, 256, 0, stream>>>(W, b, WtF);
    init_kernel<<<(N_NODES * 64 / 4 + 255) / 256, 256, 0, stream>>>(h, out);
    edge_kernel<<<(N_EDGES + BM - 1) / BM, 256, 0, stream>>>(ea, h, ei, WtF, out);
    ln_kernel<<<(N_NODES + 3) / 4, 256, 0, stream>>>(gamma, beta, out);
}

// Round 8
// 158.146 us; speedup vs baseline: 4.9195x; 1.0480x over previous
//
#include <hip/hip_runtime.h>
#include <math.h>

#define N_NODES 50000
#define N_EDGES 150000
#define LN_EPS 1e-5f

#define BM 256   // edge rows per block
#define WM 64    // edge rows per wave (4 waves)

typedef _Float16 f16x8 __attribute__((ext_vector_type(8)));
typedef _Float16 f16x4 __attribute__((ext_vector_type(4)));
typedef _Float16 f16x2 __attribute__((ext_vector_type(2)));
typedef float    f32x4 __attribute__((ext_vector_type(4)));

// cvt_pkrtz returns __fp16-based vector; convert element-wise to _Float16 type
static __device__ __forceinline__ f16x2 pkrtz(float a, float b) {
    auto p = __builtin_amdgcn_cvt_pkrtz(a, b);
    f16x2 r; r[0] = (_Float16)p[0]; r[1] = (_Float16)p[1];
    return r;
}

// ---------------------------------------------------------------------------
// prep: WtF in exact MFMA B-fragment order, one f16x8 (16B) store per thread.
//   frag index (c*4 + nb)*64 + l ; element i: k = (l>>4)*8 + i, e = nb*16 + (l&15)
//   c < 64 : W[(e*64 + c)*32 + k]      (product chunks, f == c)
//   c >= 64: b[e*64 + (c-64)*32 + k]   (bias chunks, A = h_j)
// ---------------------------------------------------------------------------
__global__ void prep_kernel(const float* __restrict__ W, const float* __restrict__ b,
                            f16x8* __restrict__ WtF) {
    int tid = blockIdx.x * 256 + threadIdx.x;
    if (tid >= 66 * 4 * 64) return;
    int l  = tid & 63;
    int nb = (tid >> 6) & 3;
    int c  = tid >> 8;
    int k0 = (l >> 4) << 3;
    int e  = nb * 16 + (l & 15);
    const float* src = (c < 64) ? &W[(e * 64 + c) * 32 + k0]
                                : &b[e * 64 + (c - 64) * 32 + k0];
    float4 v0 = *(const float4*)src;
    float4 v1 = *(const float4*)(src + 4);
    f16x8 o;
    o[0] = (_Float16)v0.x; o[1] = (_Float16)v0.y; o[2] = (_Float16)v0.z; o[3] = (_Float16)v0.w;
    o[4] = (_Float16)v1.x; o[5] = (_Float16)v1.y; o[6] = (_Float16)v1.z; o[7] = (_Float16)v1.w;
    WtF[tid] = o;
}

// ---------------------------------------------------------------------------
// init: out = h (residual base; edge kernel atomically accumulates)
// ---------------------------------------------------------------------------
__global__ void init_kernel(const float* __restrict__ h, float* __restrict__ out) {
    int tid = blockIdx.x * 256 + threadIdx.x;
    ((float4*)out)[tid] = ((const float4*)h)[tid];
}

// ---------------------------------------------------------------------------
// edge: fp16 MFMA GEMM. 4 waves x 64 rows (halves per-row B-traffic vs WM=32),
// hj staged in LDS as f16, A-fragments via v_pk_mul_f16, 3-deep B prefetch.
// ---------------------------------------------------------------------------
__launch_bounds__(256, 3)
__global__ void edge_kernel(const float* __restrict__ ea,   // [N_EDGES][32]
                            const float* __restrict__ h,    // [N_NODES][64]
                            const int*   __restrict__ ei,   // [2][N_EDGES]
                            const f16x8* __restrict__ WtF,  // fragment-major
                            float* __restrict__ out)        // [N_NODES][64]
{
    __shared__ _Float16 s_hj[BM][68];  // stride 68 f16: col reads conflict-free (banks 2*r16)
    __shared__ int      s_src[BM];

    const int t = threadIdx.x;
    const int m_base = blockIdx.x * BM;

    // ---- stage gathered h_j rows (f32 -> f16) + src indices, one row/thread ----
    {
        int gm = m_base + t;
        if (gm < N_EDGES) {
            s_src[t] = ei[gm];
            const float4* hr = (const float4*)&h[(size_t)ei[N_EDGES + gm] * 64];
            #pragma unroll
            for (int j = 0; j < 16; ++j) {
                float4 v = hr[j];
                f16x2 p0 = pkrtz(v.x, v.y);
                f16x2 p1 = pkrtz(v.z, v.w);
                f16x4 o; o[0] = p0[0]; o[1] = p0[1]; o[2] = p1[0]; o[3] = p1[1];
                *(f16x4*)&s_hj[t][j * 4] = o;   // 8B-aligned (136t + 8j)
            }
        } else {
            s_src[t] = -1;
            f16x4 z = (f16x4){0, 0, 0, 0};
            #pragma unroll
            for (int j = 0; j < 16; ++j)
                *(f16x4*)&s_hj[t][j * 4] = z;
        }
    }

    const int lane = t & 63;
    const int w    = t >> 6;
    const int r16  = lane & 15;
    const int g    = lane >> 4;
    const int k0   = g * 8;
    const int row0 = w * WM;
    int rows[4];
    #pragma unroll
    for (int a = 0; a < 4; ++a) rows[a] = row0 + a * 16 + r16;

    // ---- ea A-slices as f16 pairs: fixed per lane for the whole K loop ----
    f16x2 eap[4][4];
    #pragma unroll
    for (int a = 0; a < 4; ++a) {
        int gm = m_base + rows[a];
        if (gm < N_EDGES) {
            float4 v0 = *(const float4*)&ea[(size_t)gm * 32 + k0];
            float4 v1 = *(const float4*)&ea[(size_t)gm * 32 + k0 + 4];
            eap[a][0] = pkrtz(v0.x, v0.y);
            eap[a][1] = pkrtz(v0.z, v0.w);
            eap[a][2] = pkrtz(v1.x, v1.y);
            eap[a][3] = pkrtz(v1.z, v1.w);
        } else {
            #pragma unroll
            for (int i = 0; i < 4; ++i) eap[a][i] = (f16x2){0, 0};
        }
    }

    f32x4 acc[4][4];
    #pragma unroll
    for (int a = 0; a < 4; ++a)
        #pragma unroll
        for (int nb = 0; nb < 4; ++nb)
            acc[a][nb] = (f32x4){0.f, 0.f, 0.f, 0.f};

    __syncthreads();   // only barrier in the kernel

    // ---- B prefetch buffers (3-deep, from L2-resident WtF) ----
    f16x8 b0[4], b1[4], b2[4];
    #pragma unroll
    for (int nb = 0; nb < 4; ++nb) b0[nb] = WtF[(0 * 4 + nb) * 64 + lane];
    #pragma unroll
    for (int nb = 0; nb < 4; ++nb) b1[nb] = WtF[(1 * 4 + nb) * 64 + lane];
    #pragma unroll
    for (int nb = 0; nb < 4; ++nb) b2[nb] = WtF[(2 * 4 + nb) * 64 + lane];

    _Float16 hc[4];
    #pragma unroll
    for (int a = 0; a < 4; ++a) hc[a] = s_hj[rows[a]][0];

    // product-chunk step: compute chunk c with B-regs bb, read hj col c+1
    auto step = [&](int c, f16x8* bb, bool loadnext) {
        _Float16 hn[4] = {0, 0, 0, 0};
        if (loadnext) {
            #pragma unroll
            for (int a = 0; a < 4; ++a) hn[a] = s_hj[rows[a]][c + 1];
        }
        #pragma unroll
        for (int a = 0; a < 4; ++a) {
            f16x2 hs; hs[0] = hc[a]; hs[1] = hc[a];
            f16x2 p0 = eap[a][0] * hs;
            f16x2 p1 = eap[a][1] * hs;
            f16x2 p2 = eap[a][2] * hs;
            f16x2 p3 = eap[a][3] * hs;
            f16x8 va;
            va[0] = p0[0]; va[1] = p0[1]; va[2] = p1[0]; va[3] = p1[1];
            va[4] = p2[0]; va[5] = p2[1]; va[6] = p3[0]; va[7] = p3[1];
            #pragma unroll
            for (int nb = 0; nb < 4; ++nb)
                acc[a][nb] = __builtin_amdgcn_mfma_f32_16x16x32_f16(va, bb[nb], acc[a][nb], 0, 0, 0);
        }
        #pragma unroll
        for (int a = 0; a < 4; ++a) hc[a] = hn[a];
    };

    // ---- main loop: 21 triples cover product chunks 0..62; prefetch to 65 ----
    for (int c = 0; c < 63; c += 3) {
        step(c, b0, true);
        #pragma unroll
        for (int nb = 0; nb < 4; ++nb) b0[nb] = WtF[((c + 3) * 4 + nb) * 64 + lane];
        step(c + 1, b1, true);
        #pragma unroll
        for (int nb = 0; nb < 4; ++nb) b1[nb] = WtF[((c + 4) * 4 + nb) * 64 + lane];
        step(c + 2, b2, true);
        #pragma unroll
        for (int nb = 0; nb < 4; ++nb) b2[nb] = WtF[((c + 5) * 4 + nb) * 64 + lane];
    }
    // after loop: b0 = chunk 63 (product), b1 = 64 (bias), b2 = 65 (bias)
    step(63, b0, false);

    // ---- bias chunks: A = h_j (f16, straight from LDS) ----
    #pragma unroll
    for (int half = 0; half < 2; ++half) {
        f16x8* bb = half ? b2 : b1;
        #pragma unroll
        for (int a = 0; a < 4; ++a) {
            f16x4 lo = *(const f16x4*)&s_hj[rows[a]][half * 32 + k0];
            f16x4 hi = *(const f16x4*)&s_hj[rows[a]][half * 32 + k0 + 4];
            f16x8 va;
            va[0] = lo[0]; va[1] = lo[1]; va[2] = lo[2]; va[3] = lo[3];
            va[4] = hi[0]; va[5] = hi[1]; va[6] = hi[2]; va[7] = hi[3];
            #pragma unroll
            for (int nb = 0; nb < 4; ++nb)
                acc[a][nb] = __builtin_amdgcn_mfma_f32_16x16x32_f16(va, bb[nb], acc[a][nb], 0, 0, 0);
        }
    }

    // ---- scatter-add (C/D layout: col = lane&15, row = (lane>>4)*4 + reg) ----
    #pragma unroll
    for (int a = 0; a < 4; ++a) {
        #pragma unroll
        for (int r = 0; r < 4; ++r) {
            int srcn = s_src[row0 + a * 16 + g * 4 + r];
            if (srcn >= 0) {
                #pragma unroll
                for (int nb = 0; nb < 4; ++nb)
                    atomicAdd(&out[(size_t)srcn * 64 + nb * 16 + r16], acc[a][nb][r]);
            }
        }
    }
}

// ---------------------------------------------------------------------------
// ln: in-place LayerNorm, one wave per row
// ---------------------------------------------------------------------------
__global__ void ln_kernel(const float* __restrict__ gamma, const float* __restrict__ beta,
                          float* __restrict__ out) {
    int row = blockIdx.x * 4 + (threadIdx.x >> 6);
    int lane = threadIdx.x & 63;
    if (row >= N_NODES) return;
    float x = out[row * 64 + lane];
    float s = x;
    #pragma unroll
    for (int o = 32; o; o >>= 1) s += __shfl_xor(s, o);
    float mu = s * (1.0f / 64.0f);
    float d = x - mu;
    float v = d * d;
    #pragma unroll
    for (int o = 32; o; o >>= 1) v += __shfl_xor(v, o);
    float var = v * (1.0f / 64.0f);
    float r = rsqrtf(var + LN_EPS);
    out[row * 64 + lane] = d * r * gamma[lane] + beta[lane];
}

// ---------------------------------------------------------------------------
extern "C" void kernel_launch(void* const* d_in, const int* in_sizes, int n_in,
                              void* d_out, int out_size, void* d_ws, size_t ws_size,
                              hipStream_t stream) {
    const float* h     = (const float*)d_in[0];
    const float* ea    = (const float*)d_in[1];
    const float* W     = (const float*)d_in[2];
    const float* b     = (const float*)d_in[3];
    const float* gamma = (const float*)d_in[4];
    const float* beta  = (const float*)d_in[5];
    const int*   ei    = (const int*)d_in[6];
    float* out = (float*)d_out;

    f16x8* WtF = (f16x8*)d_ws;   // 66*4*64 f16x8 = 264 KB

    prep_kernel<<<66, 256, 0, stream>>>(W, b, WtF);
    init_kernel<<<(N_NODES * 64 / 4 + 255) / 256, 256, 0, stream>>>(h, out);
    edge_kernel<<<(N_EDGES + BM - 1) / BM, 256, 0, stream>>>(ea, h, ei, WtF, out);
    ln_kernel<<<(N_NODES + 3) / 4, 256, 0, stream>>>(gamma, beta, out);
}